// Round 10
// baseline (215.867 us; speedup 1.0000x reference)
//
#include <hip/hip_runtime.h>

#define N_DRUG 572
#define DIM 512
#define MAXDEG 32
#define FS 17            // scan LDS stride: 16 cols + 1 pad

// ---------------------------------------------------------------------------
// fwd_kernel: fused q = drugE@Wa -> attention -> agg -> h = [agg|de]@linW
// 286 blocks x 512 threads; block b handles drugs 2b, 2b+1.
// Split-K 4-way on both matmuls; per-drug input planes in LDS (broadcast
// reads); float4 weight streams with 8-deep unroll for MLP.
// ---------------------------------------------------------------------------
__global__ __launch_bounds__(512) void fwd_kernel(
    const float* __restrict__ drugW, const float* __restrict__ relaW,
    const float* __restrict__ entW, const float* __restrict__ Wa,
    const float* __restrict__ linW, const float* __restrict__ linb,
    const int* __restrict__ drug_name, const int* __restrict__ adj_tail,
    const int* __restrict__ adj_rel, float* __restrict__ out)
{
    __shared__ float cin[2][1024];    // [d][k]: k<512 agg, k>=512 drug_e
    __shared__ float red[4][2][512];  // [kh][d][col] split-K partials
    __shared__ float qs[2][512];      // q per drug
    __shared__ float at[2][64];       // scores -> attn weights
    __shared__ int   tails[2][64];
    __shared__ int   rels[2][64];

    const int t  = threadIdx.x;
    const int n0 = blockIdx.x * 2;
    const int c4 = (t & 127) * 4;     // col quad
    const int kh = t >> 7;            // k quarter 0..3

    // ---- stage drug_e planes + adjacency ----
    #pragma unroll
    for (int d = 0; d < 2; ++d) {
        const int rd = drug_name[n0 + d];
        cin[d][512 + t] = drugW[(size_t)rd * 512 + t];
    }
    if (t < 128) {
        const int d = t >> 6, kk = t & 63;
        tails[d][kk] = adj_tail[(n0 + d) * 64 + kk];
        rels[d][kk]  = adj_rel[(n0 + d) * 64 + kk];
    }
    __syncthreads();

    // ---- phase 2: q = drug_e @ Wa (split-K 4, 128 k each, unroll 8) ----
    {
        float acc[2][4] = {{0.f}};     // [d][col_i]
        const float* wp = Wa + (size_t)(kh * 128) * 512 + c4;
        const int kb = 512 + kh * 128;
        for (int k0 = 0; k0 < 128; k0 += 8) {
            float4 ww[8];
            #pragma unroll
            for (int u = 0; u < 8; ++u)
                ww[u] = *(const float4*)(wp + (size_t)(k0 + u) * 512);
            #pragma unroll
            for (int u = 0; u < 8; ++u) {
                const float4 w = ww[u];
                #pragma unroll
                for (int d = 0; d < 2; ++d) {
                    const float b = cin[d][kb + k0 + u];   // wave-uniform bcast
                    acc[d][0] = fmaf(b, w.x, acc[d][0]);
                    acc[d][1] = fmaf(b, w.y, acc[d][1]);
                    acc[d][2] = fmaf(b, w.z, acc[d][2]);
                    acc[d][3] = fmaf(b, w.w, acc[d][3]);
                }
            }
        }
        #pragma unroll
        for (int d = 0; d < 2; ++d)
            *(float4*)&red[kh][d][c4] = make_float4(acc[d][0], acc[d][1], acc[d][2], acc[d][3]);
    }
    __syncthreads();
    #pragma unroll
    for (int d = 0; d < 2; ++d)
        qs[d][t] = red[0][d][t] + red[1][d][t] + red[2][d][t] + red[3][d][t];
    __syncthreads();

    // ---- phase 3: scores (wave w: drug w>>2, 16-score quarter w&3) ----
    {
        const int w = t >> 6, lane = t & 63;
        const int d = w >> 2;
        float qv[8];
        {
            const float4* qp = (const float4*)&qs[d][lane * 8];
            const float4 x = qp[0], y = qp[1];
            qv[0]=x.x; qv[1]=x.y; qv[2]=x.z; qv[3]=x.w;
            qv[4]=y.x; qv[5]=y.y; qv[6]=y.z; qv[7]=y.w;
        }
        #pragma unroll 4
        for (int kk = 0; kk < 16; ++kk) {
            const int k = (w & 3) * 16 + kk;
            const float4* p = (const float4*)(relaW + (size_t)rels[d][k] * 512 + lane * 8);
            const float4 x = p[0], y = p[1];
            float s = 0.f;
            s = fmaf(qv[0], x.x, s); s = fmaf(qv[1], x.y, s);
            s = fmaf(qv[2], x.z, s); s = fmaf(qv[3], x.w, s);
            s = fmaf(qv[4], y.x, s); s = fmaf(qv[5], y.y, s);
            s = fmaf(qv[6], y.z, s); s = fmaf(qv[7], y.w, s);
            #pragma unroll
            for (int off = 32; off >= 1; off >>= 1) s += __shfl_xor(s, off, 64);
            if (lane == 0) at[d][k] = s * 0.0441941738241592f;  // 1/sqrt(512)
        }
    }
    __syncthreads();

    // ---- softmax per drug (waves 0 and 4) ----
    {
        const int w = t >> 6, lane = t & 63;
        if ((w & 3) == 0) {
            const int d = w >> 2;
            const float s = at[d][lane];
            float m = s;
            #pragma unroll
            for (int off = 32; off >= 1; off >>= 1) m = fmaxf(m, __shfl_xor(m, off, 64));
            const float e = __expf(s - m);
            float sum = e;
            #pragma unroll
            for (int off = 32; off >= 1; off >>= 1) sum += __shfl_xor(sum, off, 64);
            at[d][lane] = e / sum;
        }
    }
    __syncthreads();

    // ---- phase 4: agg gather (drug = t>>8, col pair = (t&255)*2) ----
    {
        const int d = t >> 8;
        const int cg = (t & 255) * 2;
        float a0 = 0.f, a1 = 0.f;
        #pragma unroll 8
        for (int k = 0; k < 64; ++k) {
            const float ak = at[d][k];
            const float2 e = *(const float2*)(entW + (size_t)tails[d][k] * 512 + cg);
            a0 = fmaf(ak, e.x, a0); a1 = fmaf(ak, e.y, a1);
        }
        *(float2*)&cin[d][cg] = make_float2(a0, a1);   // conflict-free b64
    }
    __syncthreads();

    // ---- phase 5: h = [agg|de] @ linW (split-K 4, 256 k each, unroll 8) ----
    {
        float acc[2][4] = {{0.f}};
        const int kb = kh * 256;
        const float* wp = linW + (size_t)kb * 512 + c4;
        for (int k0 = 0; k0 < 256; k0 += 8) {
            float4 ww[8];
            #pragma unroll
            for (int u = 0; u < 8; ++u)
                ww[u] = *(const float4*)(wp + (size_t)(k0 + u) * 512);
            #pragma unroll
            for (int u = 0; u < 8; ++u) {
                const float4 w = ww[u];
                #pragma unroll
                for (int d = 0; d < 2; ++d) {
                    const float b = cin[d][kb + k0 + u];
                    acc[d][0] = fmaf(b, w.x, acc[d][0]);
                    acc[d][1] = fmaf(b, w.y, acc[d][1]);
                    acc[d][2] = fmaf(b, w.z, acc[d][2]);
                    acc[d][3] = fmaf(b, w.w, acc[d][3]);
                }
            }
        }
        #pragma unroll
        for (int d = 0; d < 2; ++d)
            *(float4*)&red[kh][d][c4] = make_float4(acc[d][0], acc[d][1], acc[d][2], acc[d][3]);
    }
    __syncthreads();
    {
        const float bb = linb[t];
        #pragma unroll
        for (int d = 0; d < 2; ++d) {
            const float v = red[0][d][t] + red[1][d][t] + red[2][d][t] + red[3][d][t] + bb;
            out[(size_t)(n0 + d) * 512 + t] = fmaxf(v, 0.f);
        }
    }
}

// ---------------------------------------------------------------------------
// Fused BN + sequential smoothing scan. 32 blocks x 16 cols, 512 threads.
// u16 neighbor offsets PRE-SCALED by FS (row*17 <= 9724 fits u16).
// Unchanged from round 9 (measured: conflicts 9K, <66 us).
// ---------------------------------------------------------------------------
__global__ __launch_bounds__(512) void scan_kernel(
    float* hout, const float* __restrict__ gamma, const float* __restrict__ beta,
    const int* __restrict__ nbr_idx, const int* __restrict__ nbr_deg,
    const int* __restrict__ epoch)
{
    __shared__ float fs[(N_DRUG + 1) * FS];      // row N_DRUG = zeros (dummy)
    __shared__ alignas(16) unsigned short offs[N_DRUG * MAXDEG];  // row*FS, dummy=N_DRUG*FS
    __shared__ float2 ivw[N_DRUG];               // (0.5/deg, 0.5) or (0,1)
    __shared__ int   mxs[N_DRUG];                // max lower-dep row, -1 if none
    __shared__ float part[2][32][16];
    __shared__ float bnp[2][16];
    __shared__ int   genext[2];
    __shared__ int   ge0s;

    const int t  = threadIdx.x;
    const int c  = t & 15;
    const int h  = (t >> 4) & 1;
    const int j  = t >> 5;         // node slot 0..15
    const int rr = t >> 4;         // staging row-group 0..31
    const int c0 = blockIdx.x * 16;

    // ---- phase 0a: padded, pre-scaled u16 neighbor table; mx; ivw ----
    for (int i = t; i < N_DRUG; i += 512) {
        const int d = nbr_deg[i];
        ivw[i] = (d > 0) ? make_float2(0.5f / (float)d, 0.5f) : make_float2(0.f, 1.f);
        const int4* np = (const int4*)&nbr_idx[i * MAXDEG];
        unsigned* op = (unsigned*)&offs[i * MAXDEG];
        int mx = -1;
        #pragma unroll
        for (int u = 0; u < 8; ++u) {
            int4 qq = np[u];
            const int b = u * 4;
            qq.x = (b + 0 < d) ? qq.x : N_DRUG;
            qq.y = (b + 1 < d) ? qq.y : N_DRUG;
            qq.z = (b + 2 < d) ? qq.z : N_DRUG;
            qq.w = (b + 3 < d) ? qq.w : N_DRUG;
            mx = max(mx, (qq.x < i) ? qq.x : -1);
            mx = max(mx, (qq.y < i) ? qq.y : -1);
            mx = max(mx, (qq.z < i) ? qq.z : -1);
            mx = max(mx, (qq.w < i) ? qq.w : -1);
            op[2 * u]     = (unsigned)(qq.x * FS) | ((unsigned)(qq.y * FS) << 16);
            op[2 * u + 1] = (unsigned)(qq.z * FS) | ((unsigned)(qq.w * FS) << 16);
        }
        mxs[i] = mx;
    }

    // ---- phase 0b: stage fs (already bias+ReLU'd); partial stats ----
    {
        float sl = 0.f, ql = 0.f;
        for (int r = rr; r < N_DRUG; r += 32) {
            const float v = hout[(size_t)r * DIM + c0 + c];
            fs[r * FS + c] = v;
            sl += v;
            ql = fmaf(v, v, ql);
        }
        part[0][rr][c] = sl;
        part[1][rr][c] = ql;
    }
    if (t < FS) fs[N_DRUG * FS + t] = 0.f;
    __syncthreads();

    // ---- phase 1: stats finalize (t<16) || first group boundary (wave 7) ----
    if (t < 16) {
        float s = 0.f, sq = 0.f;
        #pragma unroll
        for (int k = 0; k < 32; ++k) { s += part[0][k][t]; sq += part[1][k][t]; }
        const float mean = s * (1.f / N_DRUG);
        const float var = sq * (1.f / N_DRUG) - mean * mean;
        const float rstd = rsqrtf(var + 1e-5f);
        const float scl = gamma[c0 + t] * rstd;
        bnp[0][t] = scl;
        bnp[1][t] = beta[c0 + t] - mean * scl;
    }
    if ((t >> 6) == 7) {
        const int l = t & 63;
        const int jj = 1 + l;
        const bool flag = (l >= 15) || (jj >= N_DRUG) || (mxs[min(jj, N_DRUG - 1)] >= 0);
        const unsigned long long b = __ballot(flag) & 0xFFFFULL;
        if (l == 0) ge0s = 1 + (int)__builtin_ctzll(b);
    }
    __syncthreads();

    // ---- phase 2: BN apply ----
    {
        const float scl = bnp[0][c];
        const float shf = bnp[1][c];
        for (int r = rr; r < N_DRUG; r += 32)
            fs[r * FS + c] = fmaf(fs[r * FS + c], scl, shf);
    }
    __syncthreads();

    // ---- rounds ----
    if (epoch[0] > 1) {
        int gs = 0, ge = ge0s;
        uint4 ca, cb;
        {
            const uint4* p = (const uint4*)&offs[min(j, N_DRUG - 1) * MAXDEG + h * 16];
            ca = p[0]; cb = p[1];
        }
        int par = 0;
        while (gs < N_DRUG) {
            const bool pred = (gs + j) < ge;
            float s0 = 0.f, s1 = 0.f;
#define G2(W) { s0 += fs[(W & 0xffffu) + c]; s1 += fs[(W >> 16) + c]; }
            if (pred) { G2(ca.x) G2(ca.y) G2(ca.z) G2(ca.w)
                        G2(cb.x) G2(cb.y) G2(cb.z) G2(cb.w) }
#undef G2
            uint4 na, nb;
            {
                const uint4* p = (const uint4*)&offs[min(ge + j, N_DRUG - 1) * MAXDEG + h * 16];
                na = p[0]; nb = p[1];
            }
            float nv = 0.f;
            if (pred) {
                const float cur = fs[(gs + j) * FS + c];
                const float2 iw = ivw[gs + j];
                float sh = s0 + s1;
                sh += __shfl_xor(sh, 16, 64);    // combine the two halves
                nv = fmaf(sh, iw.x, cur * iw.y);
            }
            if ((t >> 6) == 7) {
                const int l = t & 63;
                const int jj = ge + 1 + l;
                const bool flag = (l >= 15) || (jj >= N_DRUG) ||
                                  (mxs[min(jj, N_DRUG - 1)] >= ge);
                const unsigned long long b = __ballot(flag) & 0xFFFFULL;
                if (l == 0) genext[par] = ge + 1 + (int)__builtin_ctzll(b);
            }
            __syncthreads();   // all reads done before any write (anti-deps)
            if (pred && h == 0) fs[(gs + j) * FS + c] = nv;
            __syncthreads();   // writes + genext visible
            gs = ge;
            ge = genext[par];
            par ^= 1;
            ca = na; cb = nb;
        }
    }
    __syncthreads();

    // ---- write back ----
    for (int r = rr; r < N_DRUG; r += 32)
        hout[(size_t)r * DIM + c0 + c] = fs[r * FS + c];
}

extern "C" void kernel_launch(void* const* d_in, const int* in_sizes, int n_in,
                              void* d_out, int out_size, void* d_ws, size_t ws_size,
                              hipStream_t stream)
{
    const float* drugW = (const float*)d_in[0];
    const float* relaW = (const float*)d_in[1];
    const float* entW  = (const float*)d_in[2];
    const float* Wa    = (const float*)d_in[3];
    const float* linW  = (const float*)d_in[4];
    const float* linb  = (const float*)d_in[5];
    const float* gamma = (const float*)d_in[6];
    const float* beta  = (const float*)d_in[7];
    const int* drug_name = (const int*)d_in[8];
    const int* adj_tail  = (const int*)d_in[9];
    const int* adj_rel   = (const int*)d_in[10];
    const int* nbr_idx   = (const int*)d_in[11];
    const int* nbr_deg   = (const int*)d_in[12];
    const int* epoch     = (const int*)d_in[13];

    float* out = (float*)d_out;    // h lives in d_out; scan updates in place

    fwd_kernel<<<N_DRUG / 2, 512, 0, stream>>>(
        drugW, relaW, entW, Wa, linW, linb, drug_name, adj_tail, adj_rel, out);
    scan_kernel<<<32, 512, 0, stream>>>(
        out, gamma, beta, nbr_idx, nbr_deg, epoch);
}